// Round 13
// baseline (381.646 us; speedup 1.0000x reference)
//
#include <hip/hip_runtime.h>
#include <hip/hip_fp16.h>

#define NUM_USERS 100000
#define NUM_ITEMS 50000
#define N_NODES   150000
#define EMB_DIM   64
#define NNZ       4800000
#define N_LAYERS  3

#define TILE_ROWS 256
#define TILE_SHIFT 8
#define NTILES    ((N_NODES + TILE_ROWS - 1) / TILE_ROWS)   // 586
#define COL_BITS  18
#define COL_MASK  ((1 << COL_BITS) - 1)
#define VAL_BITS  14
#define VAL_MASK  ((1 << VAL_BITS) - 1)
#define PAD       10240     // padded per-tile capacity (avg 8192, sigma ~90)

// column-bucket sort parameters (round 13)
#define CB_SHIFT  13                     // 8192 columns (1 MB of x) per bucket
#define NBKT      32                     // 2^18 / 2^13
#define NBINS     (TILE_ROWS * NBKT)     // 8192 bins per tile

static constexpr size_t TOTAL = (size_t)N_NODES * EMB_DIM;   // 9,600,000 floats

typedef long long ll1;   // nontemporal-compatible 8B scalar

// ---------------- init: cur16 = fp16(concat) ----------------
__global__ void lgcn_init_h(const float4* __restrict__ user_emb,
                            const float4* __restrict__ item_emb,
                            uint2* __restrict__ cur16) {
    size_t i = (size_t)blockIdx.x * blockDim.x + threadIdx.x;
    const size_t n4 = TOTAL / 4;
    if (i >= n4) return;
    const size_t ub4 = (size_t)NUM_USERS * EMB_DIM / 4;
    float4 v = (i < ub4) ? user_emb[i] : item_emb[i - ub4];
    __half2 h0 = __floats2half2_rn(v.x, v.y);
    __half2 h1 = __floats2half2_rn(v.z, v.w);
    uint2 u;
    u.x = *reinterpret_cast<unsigned int*>(&h0);
    u.y = *reinterpret_cast<unsigned int*>(&h1);
    cur16[i] = u;
}

// ---------------- pass 1: LDS-staged bucketing into PADDED per-tile regions ----------------
#define BKT_BLK 1024
#define EPB     8192    // edges per block (8 per thread)

__global__ __launch_bounds__(BKT_BLK) void
edge_bucket(const int* __restrict__ rows, const int* __restrict__ cols,
            const float* __restrict__ vals, int* __restrict__ tile_cursor,
            int2* __restrict__ ebuf1) {
    __shared__ int2 stage[EPB];     // 64 KB
    __shared__ int  dstIdx[EPB];    // 32 KB
    __shared__ int  hcur[NTILES];
    __shared__ int  lbase[NTILES];
    __shared__ int  gbase[NTILES];

    int tid = threadIdx.x;
    size_t blockStart = (size_t)blockIdx.x * EPB;

    int r[8]; int c[8]; float v[8];
    for (int i = tid; i < NTILES; i += BKT_BLK) hcur[i] = 0;
    __syncthreads();

    #pragma unroll
    for (int k = 0; k < 8; k++) {
        size_t e = blockStart + (size_t)k * BKT_BLK + tid;
        if (e < NNZ) {
            r[k] = __builtin_nontemporal_load(&rows[e]);
            c[k] = __builtin_nontemporal_load(&cols[e]);
            v[k] = __builtin_nontemporal_load(&vals[e]);
            atomicAdd(&hcur[r[k] >> TILE_SHIFT], 1);
        } else r[k] = -1;
    }
    __syncthreads();

    int cnt = (tid < NTILES) ? hcur[tid] : 0;
    for (int off = 1; off < 1024; off <<= 1) {
        int add = (tid >= off && tid < NTILES) ? hcur[tid - off] : 0;
        __syncthreads();
        if (tid < NTILES) hcur[tid] += add;
        __syncthreads();
    }
    if (tid < NTILES) {
        int ex = hcur[tid] - cnt;
        lbase[tid] = ex;
        gbase[tid] = cnt ? (tid * PAD + atomicAdd(&tile_cursor[tid], cnt)) : 0;
    }
    __syncthreads();
    if (tid < NTILES) hcur[tid] = lbase[tid];
    __syncthreads();

    #pragma unroll
    for (int k = 0; k < 8; k++) {
        if (r[k] >= 0) {
            int t = r[k] >> TILE_SHIFT;
            int slot = atomicAdd(&hcur[t], 1);
            stage[slot] = make_int2(((r[k] & (TILE_ROWS - 1)) << COL_BITS) | c[k],
                                    __float_as_int(v[k]));
            dstIdx[slot] = gbase[t] + (slot - lbase[t]);
        }
    }
    __syncthreads();

    int total = (int)min((size_t)EPB, (size_t)NNZ - blockStart);
    for (int i = tid; i < total; i += BKT_BLK)
        ebuf1[dstIdx[i]] = stage[i];   // coalesced within per-tile runs
}

// ---------------- scan of padded-bucket counts -> compact tile_ptr ----------------
__global__ void tile_scan(const int* __restrict__ counts,
                          int* __restrict__ tile_ptr,
                          int* __restrict__ row_ptr) {
    __shared__ int s[1024];
    int t = threadIdx.x;
    int v = (t < NTILES) ? counts[t] : 0;
    s[t] = v;
    __syncthreads();
    for (int off = 1; off < 1024; off <<= 1) {
        int add = (t >= off) ? s[t - off] : 0;
        __syncthreads();
        s[t] += add;
        __syncthreads();
    }
    if (t < NTILES) tile_ptr[t] = s[t] - v;   // exclusive
    if (t == 0) {
        tile_ptr[NTILES] = NNZ;
        row_ptr[N_NODES] = NNZ;
    }
}

// ---------------- pass 2: counting sort by (row, col-bucket); emits row_ptr + packed 4B edges ----
// edge word: col(18b) << 14 | fp16_bits(val) (val < 2.0 => bits < 0x4000)
// Sorting each row's edges by column bucket creates a synchronized column band
// across concurrently-running SpMM waves -> gather working set fits per-XCD L2.
#define RS_BLK 512
#define BINS_PER_THREAD (NBINS / RS_BLK)   // 16

__global__ __launch_bounds__(RS_BLK) void
row_sort(const int2* __restrict__ ebuf1, const int* __restrict__ tile_ptr,
         int* __restrict__ row_ptr, unsigned int* __restrict__ epack) {
    __shared__ int hist[NBINS];     // 32 KB: count -> bin-start -> cursor
    __shared__ int tsum[RS_BLK];    // 2 KB
    int tid = threadIdx.x;
    int tile = blockIdx.x;
    int base_in = tile * PAD;
    int obase = tile_ptr[tile];
    int cnt = tile_ptr[tile + 1] - obase;
    const ll1* eb64 = reinterpret_cast<const ll1*>(ebuf1);

    for (int i = tid; i < NBINS; i += RS_BLK) hist[i] = 0;
    __syncthreads();

    for (int i = tid; i < cnt; i += RS_BLK) {
        ll1 raw = __builtin_nontemporal_load(&eb64[base_in + i]);
        unsigned int mx = (unsigned int)(unsigned long long)raw;   // .x = low 32
        int r = mx >> COL_BITS;
        int b = (mx & COL_MASK) >> CB_SHIFT;
        atomicAdd(&hist[(r << 5) | b], 1);
    }
    __syncthreads();

    // two-level exclusive scan over 8192 bins: 16 bins/thread local + block scan
    int base = tid * BINS_PER_THREAD;
    int local[BINS_PER_THREAD];
    int s = 0;
    #pragma unroll
    for (int k = 0; k < BINS_PER_THREAD; k++) { local[k] = s; s += hist[base + k]; }
    tsum[tid] = s;
    __syncthreads();
    for (int off = 1; off < RS_BLK; off <<= 1) {
        int add = (tid >= off) ? tsum[tid - off] : 0;
        __syncthreads();
        tsum[tid] += add;
        __syncthreads();
    }
    int toff = tsum[tid] - s;   // exclusive prefix of this thread's bins
    #pragma unroll
    for (int k = 0; k < BINS_PER_THREAD; k++)
        hist[base + k] = obase + toff + local[k];   // global bin start
    __syncthreads();

    // row r starts at bin (r<<5); each thread owns 16 bins = half a row
    if ((base & (NBKT - 1)) == 0) {
        int r = base >> 5;
        int rowG = tile * TILE_ROWS + r;
        if (rowG < N_NODES) row_ptr[rowG] = hist[base];
    }
    __syncthreads();

    // scatter: hist now serves as cursors
    for (int i = tid; i < cnt; i += RS_BLK) {
        ll1 raw = __builtin_nontemporal_load(&eb64[base_in + i]);
        unsigned int mx = (unsigned int)(unsigned long long)raw;
        unsigned int my = (unsigned int)((unsigned long long)raw >> 32);
        int r = mx >> COL_BITS;
        int b = (mx & COL_MASK) >> CB_SHIFT;
        int pos = atomicAdd(&hist[(r << 5) | b], 1);
        unsigned int col = mx & COL_MASK;
        unsigned int hb = (unsigned)__half_as_ushort(__float2half_rn(__uint_as_float(my)));
        if (hb > (unsigned)VAL_MASK) hb = VAL_MASK;   // defensive (val<2.0 never triggers)
        epack[pos] = (col << VAL_BITS) | hb;
    }
}

// ---------------- gather SpMM: 8 substreams x 8 lanes, 16-edge unroll for MLP ----------------
// NOTE: edges (epack) is re-read by all 3 layers — PLAIN loads, never nontemporal.
__device__ __forceinline__ void edge_fma(unsigned int m, const uint4* __restrict__ x16v,
                                         int t, __half2& a0, __half2& a1,
                                         __half2& a2, __half2& a3) {
    uint4 xv = x16v[(size_t)(m >> VAL_BITS) * 8 + t];
    unsigned int vv = (m & VAL_MASK);
    vv |= (vv << 16);
    __half2 vh = *reinterpret_cast<__half2*>(&vv);
    const __half2* xh = reinterpret_cast<const __half2*>(&xv);
    a0 = __hfma2(xh[0], vh, a0);
    a1 = __hfma2(xh[1], vh, a1);
    a2 = __hfma2(xh[2], vh, a2);
    a3 = __hfma2(xh[3], vh, a3);
}

template <int FINAL>
__global__ void lgcn_spmm_h8(const int* __restrict__ row_ptr,
                             const unsigned int* __restrict__ edges,
                             const uint4* __restrict__ x16v,
                             uint4* __restrict__ y16v,
                             const uint4* __restrict__ x0v,
                             const uint4* __restrict__ y1v,
                             const uint4* __restrict__ y2v,
                             float4* __restrict__ outv) {
    int wid = blockIdx.x * (blockDim.x >> 6) + (threadIdx.x >> 6);
    if (wid >= N_NODES) return;
    int lane = threadIdx.x & 63;
    int g = lane >> 3;       // edge substream 0..7
    int t = lane & 7;        // dim group: dims 8t..8t+7
    int e  = row_ptr[wid];
    int e1 = row_ptr[wid + 1];

    __half2 a0 = __float2half2_rn(0.0f), a1 = a0, a2 = a0, a3 = a0;

    // 16-edge main loop: two independent edge loads + two independent gathers in flight
    for (; e + 16 <= e1; e += 16) {
        unsigned int mA = edges[e + g];
        unsigned int mB = edges[e + 8 + g];
        uint4 xvA = x16v[(size_t)(mA >> VAL_BITS) * 8 + t];
        uint4 xvB = x16v[(size_t)(mB >> VAL_BITS) * 8 + t];
        unsigned int vA = (mA & VAL_MASK); vA |= (vA << 16);
        unsigned int vB = (mB & VAL_MASK); vB |= (vB << 16);
        __half2 vhA = *reinterpret_cast<__half2*>(&vA);
        __half2 vhB = *reinterpret_cast<__half2*>(&vB);
        const __half2* xhA = reinterpret_cast<const __half2*>(&xvA);
        const __half2* xhB = reinterpret_cast<const __half2*>(&xvB);
        a0 = __hfma2(xhA[0], vhA, a0);
        a1 = __hfma2(xhA[1], vhA, a1);
        a2 = __hfma2(xhA[2], vhA, a2);
        a3 = __hfma2(xhA[3], vhA, a3);
        a0 = __hfma2(xhB[0], vhB, a0);
        a1 = __hfma2(xhB[1], vhB, a1);
        a2 = __hfma2(xhB[2], vhB, a2);
        a3 = __hfma2(xhB[3], vhB, a3);
    }
    if (e + 8 <= e1) {
        edge_fma(edges[e + g], x16v, t, a0, a1, a2, a3);
        e += 8;
    }
    int rem = e1 - e;        // 0..7
    if (g < rem) {
        edge_fma(edges[e + g], x16v, t, a0, a1, a2, a3);
    }

    // fold the 8 substreams in half2 space (xor 8,16,32 flips g bits)
    #pragma unroll
    for (int mask = 8; mask <= 32; mask <<= 1) {
        unsigned int u;
        u = __shfl_xor(*reinterpret_cast<unsigned int*>(&a0), mask);
        a0 = __hadd2(a0, *reinterpret_cast<__half2*>(&u));
        u = __shfl_xor(*reinterpret_cast<unsigned int*>(&a1), mask);
        a1 = __hadd2(a1, *reinterpret_cast<__half2*>(&u));
        u = __shfl_xor(*reinterpret_cast<unsigned int*>(&a2), mask);
        a2 = __hadd2(a2, *reinterpret_cast<__half2*>(&u));
        u = __shfl_xor(*reinterpret_cast<unsigned int*>(&a3), mask);
        a3 = __hadd2(a3, *reinterpret_cast<__half2*>(&u));
    }

    if (lane < 8) {
        size_t idx = (size_t)wid * 8 + t;
        if (!FINAL) {
            // PLAIN store: y is re-read by the next layer — keep it cache-resident
            uint4 u;
            u.x = *reinterpret_cast<unsigned int*>(&a0);
            u.y = *reinterpret_cast<unsigned int*>(&a1);
            u.z = *reinterpret_cast<unsigned int*>(&a2);
            u.w = *reinterpret_cast<unsigned int*>(&a3);
            y16v[idx] = u;
        } else {
            uint4 ux = x0v[idx];
            uint4 u1 = y1v[idx];
            uint4 u2 = y2v[idx];
            const __half2* hx = reinterpret_cast<const __half2*>(&ux);
            const __half2* h1 = reinterpret_cast<const __half2*>(&u1);
            const __half2* h2 = reinterpret_cast<const __half2*>(&u2);
            __half2 av[4] = {a0, a1, a2, a3};
            float o[8];
            #pragma unroll
            for (int k = 0; k < 4; k++) {
                float2 fx = __half22float2(hx[k]);
                float2 f1 = __half22float2(h1[k]);
                float2 f2 = __half22float2(h2[k]);
                float2 fa = __half22float2(av[k]);
                o[2*k]   = (fx.x + f1.x + f2.x + fa.x) * 0.25f;
                o[2*k+1] = (fx.y + f1.y + f2.y + fa.y) * 0.25f;
            }
            float4 o0 = make_float4(o[0], o[1], o[2], o[3]);
            float4 o1 = make_float4(o[4], o[5], o[6], o[7]);
            outv[(size_t)wid * 16 + 2*t]     = o0;
            outv[(size_t)wid * 16 + 2*t + 1] = o1;
        }
    }
}

// ---------------- fallback (round-1 atomic path), used if ws too small ----------------
__global__ void lgcn_init_f(const float4* __restrict__ user_emb,
                            const float4* __restrict__ item_emb,
                            float4* __restrict__ cur,
                            float4* __restrict__ acc) {
    size_t i = (size_t)blockIdx.x * blockDim.x + threadIdx.x;
    const size_t n4 = TOTAL / 4;
    if (i >= n4) return;
    const size_t ub4 = (size_t)NUM_USERS * EMB_DIM / 4;
    float4 v = (i < ub4) ? user_emb[i] : item_emb[i - ub4];
    cur[i] = v;
    acc[i] = v;
}

__global__ void lgcn_spmm_scatter(const int* __restrict__ rows,
                                  const int* __restrict__ cols,
                                  const float* __restrict__ vals,
                                  const float* __restrict__ x,
                                  float* __restrict__ y) {
    size_t t = (size_t)blockIdx.x * blockDim.x + threadIdx.x;
    if (t >= (size_t)NNZ * EMB_DIM) return;
    int e = (int)(t >> 6);
    int d = (int)(t & 63);
    atomicAdd(&y[(size_t)rows[e] * EMB_DIM + d], vals[e] * x[(size_t)cols[e] * EMB_DIM + d]);
}

__global__ void lgcn_accum(float4* __restrict__ acc, const float4* __restrict__ nxt, float scale) {
    size_t i = (size_t)blockIdx.x * blockDim.x + threadIdx.x;
    const size_t n4 = TOTAL / 4;
    if (i >= n4) return;
    float4 a = acc[i]; float4 b = nxt[i];
    a.x = (a.x + b.x) * scale; a.y = (a.y + b.y) * scale;
    a.z = (a.z + b.z) * scale; a.w = (a.w + b.w) * scale;
    acc[i] = a;
}

extern "C" void kernel_launch(void* const* d_in, const int* in_sizes, int n_in,
                              void* d_out, int out_size, void* d_ws, size_t ws_size,
                              hipStream_t stream) {
    const float* user_emb = (const float*)d_in[0];
    const float* item_emb = (const float*)d_in[1];
    const int*   rows     = (const int*)d_in[2];
    const int*   cols     = (const int*)d_in[3];
    const float* vals     = (const float*)d_in[4];
    float* out = (float*)d_out;

    const int BLK = 256;
    const size_t n4 = TOTAL / 4;
    dim3 g_init((n4 + BLK - 1) / BLK);

    // workspace layout — y1/y2 ALIAS padded ebuf1 (dead after row_sort)
    char* p = (char*)d_ws;
    unsigned int* epack = (unsigned int*)p;  p += (size_t)NNZ * sizeof(unsigned int);        // 19.2 MB
    __half* y1 = (__half*)p;                                                                  // aliases ebuf1
    int2*   ebuf1 = (int2*)p;                p += (size_t)NTILES * PAD * sizeof(int2);        // 48.0 MB
    __half* y2 = y1 + TOTAL;                                                                  // aliases ebuf1
    __half* cur16 = (__half*)p;              p += TOTAL * sizeof(__half);                     // 19.2 MB
    int*    tile_ptr = (int*)p;              p += (size_t)(NTILES + 1) * sizeof(int);
    int*    tile_cursor = (int*)p;           p += (size_t)NTILES * sizeof(int);
    int*    row_ptr = (int*)p;               p += (size_t)(N_NODES + 1) * sizeof(int);
    size_t needed = (size_t)(p - (char*)d_ws);

    if (ws_size < needed) {
        float* fcur = (float*)d_ws;
        float* fnxt = fcur + TOTAL;
        lgcn_init_f<<<g_init, BLK, 0, stream>>>((const float4*)user_emb, (const float4*)item_emb,
                                                (float4*)fcur, (float4*)out);
        const size_t st = (size_t)NNZ * EMB_DIM;
        dim3 g_scat((st + BLK - 1) / BLK);
        for (int l = 0; l < N_LAYERS; ++l) {
            hipMemsetAsync(fnxt, 0, TOTAL * sizeof(float), stream);
            lgcn_spmm_scatter<<<g_scat, BLK, 0, stream>>>(rows, cols, vals, fcur, fnxt);
            float scale = (l == N_LAYERS - 1) ? (1.0f / (N_LAYERS + 1)) : 1.0f;
            lgcn_accum<<<g_init, BLK, 0, stream>>>((float4*)out, (const float4*)fnxt, scale);
            float* t = fcur; fcur = fnxt; fnxt = t;
        }
        return;
    }

    // ---- padded bucketing + within-tile (row, col-bucket) sort ----
    hipMemsetAsync(tile_cursor, 0, (size_t)NTILES * sizeof(int), stream);
    int nBuckBlocks = (NNZ + EPB - 1) / EPB;   // 586
    edge_bucket<<<nBuckBlocks, BKT_BLK, 0, stream>>>(rows, cols, vals, tile_cursor, ebuf1);
    tile_scan<<<1, 1024, 0, stream>>>(tile_cursor, tile_ptr, row_ptr);
    row_sort<<<NTILES, RS_BLK, 0, stream>>>(ebuf1, tile_ptr, row_ptr, epack);

    // ---- init fp16 x0 (cur16 does NOT alias ebuf1; y1/y2 do, written after row_sort) ----
    lgcn_init_h<<<g_init, BLK, 0, stream>>>((const float4*)user_emb, (const float4*)item_emb,
                                            (uint2*)cur16);

    // ---- 3 layers; final layer fuses the combine ----
    const int WAVES_PER_BLK = BLK / 64;
    dim3 g_spmm((N_NODES + WAVES_PER_BLK - 1) / WAVES_PER_BLK);
    lgcn_spmm_h8<0><<<g_spmm, BLK, 0, stream>>>(row_ptr, epack,
        (const uint4*)cur16, (uint4*)y1, nullptr, nullptr, nullptr, nullptr);
    lgcn_spmm_h8<0><<<g_spmm, BLK, 0, stream>>>(row_ptr, epack,
        (const uint4*)y1, (uint4*)y2, nullptr, nullptr, nullptr, nullptr);
    lgcn_spmm_h8<1><<<g_spmm, BLK, 0, stream>>>(row_ptr, epack,
        (const uint4*)y2, nullptr,
        (const uint4*)cur16, (const uint4*)y1, (const uint4*)y2, (float4*)out);
}

// Round 14
// 373.246 us; speedup vs baseline: 1.0225x; 1.0225x over previous
//
#include <hip/hip_runtime.h>
#include <hip/hip_fp16.h>

#define NUM_USERS 100000
#define NUM_ITEMS 50000
#define N_NODES   150000
#define EMB_DIM   64
#define NNZ       4800000
#define N_LAYERS  3

#define TILE_ROWS 256
#define TILE_SHIFT 8
#define NTILES    ((N_NODES + TILE_ROWS - 1) / TILE_ROWS)   // 586
#define COL_BITS  18
#define COL_MASK  ((1 << COL_BITS) - 1)
#define VAL_BITS  14
#define VAL_MASK  ((1 << VAL_BITS) - 1)
#define PAD       10240     // padded per-tile capacity (avg 8192, sigma ~90)

static constexpr size_t TOTAL = (size_t)N_NODES * EMB_DIM;   // 9,600,000 floats

typedef long long ll1;   // nontemporal-compatible 8B scalar

// ---------------- init: cur16 = fp16(concat) ----------------
__global__ void lgcn_init_h(const float4* __restrict__ user_emb,
                            const float4* __restrict__ item_emb,
                            uint2* __restrict__ cur16) {
    size_t i = (size_t)blockIdx.x * blockDim.x + threadIdx.x;
    const size_t n4 = TOTAL / 4;
    if (i >= n4) return;
    const size_t ub4 = (size_t)NUM_USERS * EMB_DIM / 4;
    float4 v = (i < ub4) ? user_emb[i] : item_emb[i - ub4];
    __half2 h0 = __floats2half2_rn(v.x, v.y);
    __half2 h1 = __floats2half2_rn(v.z, v.w);
    uint2 u;
    u.x = *reinterpret_cast<unsigned int*>(&h0);
    u.y = *reinterpret_cast<unsigned int*>(&h1);
    cur16[i] = u;
}

// ---------------- pass 1: LDS-staged bucketing into PADDED per-tile regions ----------------
#define BKT_BLK 1024
#define EPB     8192    // edges per block (8 per thread)

__global__ __launch_bounds__(BKT_BLK) void
edge_bucket(const int* __restrict__ rows, const int* __restrict__ cols,
            const float* __restrict__ vals, int* __restrict__ tile_cursor,
            int2* __restrict__ ebuf1) {
    __shared__ int2 stage[EPB];     // 64 KB
    __shared__ int  dstIdx[EPB];    // 32 KB
    __shared__ int  hcur[NTILES];
    __shared__ int  lbase[NTILES];
    __shared__ int  gbase[NTILES];

    int tid = threadIdx.x;
    size_t blockStart = (size_t)blockIdx.x * EPB;

    int r[8]; int c[8]; float v[8];
    for (int i = tid; i < NTILES; i += BKT_BLK) hcur[i] = 0;
    __syncthreads();

    #pragma unroll
    for (int k = 0; k < 8; k++) {
        size_t e = blockStart + (size_t)k * BKT_BLK + tid;
        if (e < NNZ) {
            r[k] = __builtin_nontemporal_load(&rows[e]);
            c[k] = __builtin_nontemporal_load(&cols[e]);
            v[k] = __builtin_nontemporal_load(&vals[e]);
            atomicAdd(&hcur[r[k] >> TILE_SHIFT], 1);
        } else r[k] = -1;
    }
    __syncthreads();

    int cnt = (tid < NTILES) ? hcur[tid] : 0;
    for (int off = 1; off < 1024; off <<= 1) {
        int add = (tid >= off && tid < NTILES) ? hcur[tid - off] : 0;
        __syncthreads();
        if (tid < NTILES) hcur[tid] += add;
        __syncthreads();
    }
    if (tid < NTILES) {
        int ex = hcur[tid] - cnt;
        lbase[tid] = ex;
        gbase[tid] = cnt ? (tid * PAD + atomicAdd(&tile_cursor[tid], cnt)) : 0;
    }
    __syncthreads();
    if (tid < NTILES) hcur[tid] = lbase[tid];
    __syncthreads();

    #pragma unroll
    for (int k = 0; k < 8; k++) {
        if (r[k] >= 0) {
            int t = r[k] >> TILE_SHIFT;
            int slot = atomicAdd(&hcur[t], 1);
            stage[slot] = make_int2(((r[k] & (TILE_ROWS - 1)) << COL_BITS) | c[k],
                                    __float_as_int(v[k]));
            dstIdx[slot] = gbase[t] + (slot - lbase[t]);
        }
    }
    __syncthreads();

    int total = (int)min((size_t)EPB, (size_t)NNZ - blockStart);
    for (int i = tid; i < total; i += BKT_BLK)
        ebuf1[dstIdx[i]] = stage[i];   // coalesced within per-tile runs
}

// ---------------- scan of padded-bucket counts -> compact tile_ptr ----------------
__global__ void tile_scan(const int* __restrict__ counts,
                          int* __restrict__ tile_ptr,
                          int* __restrict__ row_ptr) {
    __shared__ int s[1024];
    int t = threadIdx.x;
    int v = (t < NTILES) ? counts[t] : 0;
    s[t] = v;
    __syncthreads();
    for (int off = 1; off < 1024; off <<= 1) {
        int add = (t >= off) ? s[t - off] : 0;
        __syncthreads();
        s[t] += add;
        __syncthreads();
    }
    if (t < NTILES) tile_ptr[t] = s[t] - v;   // exclusive
    if (t == 0) {
        tile_ptr[NTILES] = NNZ;
        row_ptr[N_NODES] = NNZ;
    }
}

// ---------------- pass 2: within-tile sort by row; emits row_ptr + packed 4B edges ----------------
// edge word: col(18b) << 14 | fp16_bits(val) (val < 2.0 => bits < 0x4000)
#define RS_BLK 512

__global__ __launch_bounds__(RS_BLK) void
row_sort(const int2* __restrict__ ebuf1, const int* __restrict__ tile_ptr,
         int* __restrict__ row_ptr, unsigned int* __restrict__ epack) {
    __shared__ int hist[TILE_ROWS];
    __shared__ int cur256[TILE_ROWS];
    int tid = threadIdx.x;
    int tile = blockIdx.x;
    int base_in = tile * PAD;
    int obase = tile_ptr[tile];
    int cnt = tile_ptr[tile + 1] - obase;
    const ll1* eb64 = reinterpret_cast<const ll1*>(ebuf1);

    if (tid < TILE_ROWS) hist[tid] = 0;
    __syncthreads();

    for (int i = tid; i < cnt; i += RS_BLK) {
        ll1 raw = __builtin_nontemporal_load(&eb64[base_in + i]);
        unsigned int mx = (unsigned int)(unsigned long long)raw;   // .x = low 32
        atomicAdd(&hist[mx >> COL_BITS], 1);
    }
    __syncthreads();

    int v = (tid < TILE_ROWS) ? hist[tid] : 0;
    for (int off = 1; off < TILE_ROWS; off <<= 1) {
        int add = (tid >= off && tid < TILE_ROWS) ? hist[tid - off] : 0;
        __syncthreads();
        if (tid < TILE_ROWS) hist[tid] += add;
        __syncthreads();
    }
    if (tid < TILE_ROWS) {
        int excl = hist[tid] - v;
        int rowG = tile * TILE_ROWS + tid;
        if (rowG < N_NODES) row_ptr[rowG] = obase + excl;
        cur256[tid] = obase + excl;
    }
    __syncthreads();

    for (int i = tid; i < cnt; i += RS_BLK) {
        ll1 raw = __builtin_nontemporal_load(&eb64[base_in + i]);
        unsigned int mx = (unsigned int)(unsigned long long)raw;
        unsigned int my = (unsigned int)((unsigned long long)raw >> 32);
        int r = mx >> COL_BITS;
        int pos = atomicAdd(&cur256[r], 1);
        unsigned int col = mx & COL_MASK;
        unsigned int hb = (unsigned)__half_as_ushort(__float2half_rn(__uint_as_float(my)));
        if (hb > (unsigned)VAL_MASK) hb = VAL_MASK;   // defensive (val<2.0 never triggers)
        epack[pos] = (col << VAL_BITS) | hb;          // scatter within ~32KB window (L2)
    }
}

// ---------------- gather SpMM: 8 substreams x 8 lanes, 32/16/8-edge unroll for MLP ----------------
// NOTE: edges (epack) is re-read by all 3 layers — PLAIN loads, never nontemporal.
__device__ __forceinline__ void edge_fma(unsigned int m, const uint4* __restrict__ x16v,
                                         int t, __half2& a0, __half2& a1,
                                         __half2& a2, __half2& a3) {
    uint4 xv = x16v[(size_t)(m >> VAL_BITS) * 8 + t];
    unsigned int vv = (m & VAL_MASK);
    vv |= (vv << 16);
    __half2 vh = *reinterpret_cast<__half2*>(&vv);
    const __half2* xh = reinterpret_cast<const __half2*>(&xv);
    a0 = __hfma2(xh[0], vh, a0);
    a1 = __hfma2(xh[1], vh, a1);
    a2 = __hfma2(xh[2], vh, a2);
    a3 = __hfma2(xh[3], vh, a3);
}

template <int FINAL>
__global__ void lgcn_spmm_h8(const int* __restrict__ row_ptr,
                             const unsigned int* __restrict__ edges,
                             const uint4* __restrict__ x16v,
                             uint4* __restrict__ y16v,
                             const uint4* __restrict__ x0v,
                             const uint4* __restrict__ y1v,
                             const uint4* __restrict__ y2v,
                             float4* __restrict__ outv) {
    int wid = blockIdx.x * (blockDim.x >> 6) + (threadIdx.x >> 6);
    if (wid >= N_NODES) return;
    int lane = threadIdx.x & 63;
    int g = lane >> 3;       // edge substream 0..7
    int t = lane & 7;        // dim group: dims 8t..8t+7
    int e  = row_ptr[wid];
    int e1 = row_ptr[wid + 1];

    __half2 a0 = __float2half2_rn(0.0f), a1 = a0, a2 = a0, a3 = a0;

    // 32-edge main loop: 4 independent edge loads + 4 independent gathers in flight
    for (; e + 32 <= e1; e += 32) {
        unsigned int mA = edges[e + g];
        unsigned int mB = edges[e + 8 + g];
        unsigned int mC = edges[e + 16 + g];
        unsigned int mD = edges[e + 24 + g];
        uint4 xvA = x16v[(size_t)(mA >> VAL_BITS) * 8 + t];
        uint4 xvB = x16v[(size_t)(mB >> VAL_BITS) * 8 + t];
        uint4 xvC = x16v[(size_t)(mC >> VAL_BITS) * 8 + t];
        uint4 xvD = x16v[(size_t)(mD >> VAL_BITS) * 8 + t];
        unsigned int vA = (mA & VAL_MASK); vA |= (vA << 16);
        unsigned int vB = (mB & VAL_MASK); vB |= (vB << 16);
        unsigned int vC = (mC & VAL_MASK); vC |= (vC << 16);
        unsigned int vD = (mD & VAL_MASK); vD |= (vD << 16);
        __half2 vhA = *reinterpret_cast<__half2*>(&vA);
        __half2 vhB = *reinterpret_cast<__half2*>(&vB);
        __half2 vhC = *reinterpret_cast<__half2*>(&vC);
        __half2 vhD = *reinterpret_cast<__half2*>(&vD);
        const __half2* xhA = reinterpret_cast<const __half2*>(&xvA);
        const __half2* xhB = reinterpret_cast<const __half2*>(&xvB);
        const __half2* xhC = reinterpret_cast<const __half2*>(&xvC);
        const __half2* xhD = reinterpret_cast<const __half2*>(&xvD);
        a0 = __hfma2(xhA[0], vhA, a0); a1 = __hfma2(xhA[1], vhA, a1);
        a2 = __hfma2(xhA[2], vhA, a2); a3 = __hfma2(xhA[3], vhA, a3);
        a0 = __hfma2(xhB[0], vhB, a0); a1 = __hfma2(xhB[1], vhB, a1);
        a2 = __hfma2(xhB[2], vhB, a2); a3 = __hfma2(xhB[3], vhB, a3);
        a0 = __hfma2(xhC[0], vhC, a0); a1 = __hfma2(xhC[1], vhC, a1);
        a2 = __hfma2(xhC[2], vhC, a2); a3 = __hfma2(xhC[3], vhC, a3);
        a0 = __hfma2(xhD[0], vhD, a0); a1 = __hfma2(xhD[1], vhD, a1);
        a2 = __hfma2(xhD[2], vhD, a2); a3 = __hfma2(xhD[3], vhD, a3);
    }
    if (e + 16 <= e1) {
        unsigned int mA = edges[e + g];
        unsigned int mB = edges[e + 8 + g];
        uint4 xvA = x16v[(size_t)(mA >> VAL_BITS) * 8 + t];
        uint4 xvB = x16v[(size_t)(mB >> VAL_BITS) * 8 + t];
        unsigned int vA = (mA & VAL_MASK); vA |= (vA << 16);
        unsigned int vB = (mB & VAL_MASK); vB |= (vB << 16);
        __half2 vhA = *reinterpret_cast<__half2*>(&vA);
        __half2 vhB = *reinterpret_cast<__half2*>(&vB);
        const __half2* xhA = reinterpret_cast<const __half2*>(&xvA);
        const __half2* xhB = reinterpret_cast<const __half2*>(&xvB);
        a0 = __hfma2(xhA[0], vhA, a0); a1 = __hfma2(xhA[1], vhA, a1);
        a2 = __hfma2(xhA[2], vhA, a2); a3 = __hfma2(xhA[3], vhA, a3);
        a0 = __hfma2(xhB[0], vhB, a0); a1 = __hfma2(xhB[1], vhB, a1);
        a2 = __hfma2(xhB[2], vhB, a2); a3 = __hfma2(xhB[3], vhB, a3);
        e += 16;
    }
    if (e + 8 <= e1) {
        edge_fma(edges[e + g], x16v, t, a0, a1, a2, a3);
        e += 8;
    }
    int rem = e1 - e;        // 0..7
    if (g < rem) {
        edge_fma(edges[e + g], x16v, t, a0, a1, a2, a3);
    }

    // fold the 8 substreams in half2 space (xor 8,16,32 flips g bits)
    #pragma unroll
    for (int mask = 8; mask <= 32; mask <<= 1) {
        unsigned int u;
        u = __shfl_xor(*reinterpret_cast<unsigned int*>(&a0), mask);
        a0 = __hadd2(a0, *reinterpret_cast<__half2*>(&u));
        u = __shfl_xor(*reinterpret_cast<unsigned int*>(&a1), mask);
        a1 = __hadd2(a1, *reinterpret_cast<__half2*>(&u));
        u = __shfl_xor(*reinterpret_cast<unsigned int*>(&a2), mask);
        a2 = __hadd2(a2, *reinterpret_cast<__half2*>(&u));
        u = __shfl_xor(*reinterpret_cast<unsigned int*>(&a3), mask);
        a3 = __hadd2(a3, *reinterpret_cast<__half2*>(&u));
    }

    if (lane < 8) {
        size_t idx = (size_t)wid * 8 + t;
        if (!FINAL) {
            // PLAIN store: y is re-read by the next layer — keep it cache-resident
            uint4 u;
            u.x = *reinterpret_cast<unsigned int*>(&a0);
            u.y = *reinterpret_cast<unsigned int*>(&a1);
            u.z = *reinterpret_cast<unsigned int*>(&a2);
            u.w = *reinterpret_cast<unsigned int*>(&a3);
            y16v[idx] = u;
        } else {
            uint4 ux = x0v[idx];
            uint4 u1 = y1v[idx];
            uint4 u2 = y2v[idx];
            const __half2* hx = reinterpret_cast<const __half2*>(&ux);
            const __half2* h1 = reinterpret_cast<const __half2*>(&u1);
            const __half2* h2 = reinterpret_cast<const __half2*>(&u2);
            __half2 av[4] = {a0, a1, a2, a3};
            float o[8];
            #pragma unroll
            for (int k = 0; k < 4; k++) {
                float2 fx = __half22float2(hx[k]);
                float2 f1 = __half22float2(h1[k]);
                float2 f2 = __half22float2(h2[k]);
                float2 fa = __half22float2(av[k]);
                o[2*k]   = (fx.x + f1.x + f2.x + fa.x) * 0.25f;
                o[2*k+1] = (fx.y + f1.y + f2.y + fa.y) * 0.25f;
            }
            float4 o0 = make_float4(o[0], o[1], o[2], o[3]);
            float4 o1 = make_float4(o[4], o[5], o[6], o[7]);
            outv[(size_t)wid * 16 + 2*t]     = o0;
            outv[(size_t)wid * 16 + 2*t + 1] = o1;
        }
    }
}

// ---------------- fallback (round-1 atomic path), used if ws too small ----------------
__global__ void lgcn_init_f(const float4* __restrict__ user_emb,
                            const float4* __restrict__ item_emb,
                            float4* __restrict__ cur,
                            float4* __restrict__ acc) {
    size_t i = (size_t)blockIdx.x * blockDim.x + threadIdx.x;
    const size_t n4 = TOTAL / 4;
    if (i >= n4) return;
    const size_t ub4 = (size_t)NUM_USERS * EMB_DIM / 4;
    float4 v = (i < ub4) ? user_emb[i] : item_emb[i - ub4];
    cur[i] = v;
    acc[i] = v;
}

__global__ void lgcn_spmm_scatter(const int* __restrict__ rows,
                                  const int* __restrict__ cols,
                                  const float* __restrict__ vals,
                                  const float* __restrict__ x,
                                  float* __restrict__ y) {
    size_t t = (size_t)blockIdx.x * blockDim.x + threadIdx.x;
    if (t >= (size_t)NNZ * EMB_DIM) return;
    int e = (int)(t >> 6);
    int d = (int)(t & 63);
    atomicAdd(&y[(size_t)rows[e] * EMB_DIM + d], vals[e] * x[(size_t)cols[e] * EMB_DIM + d]);
}

__global__ void lgcn_accum(float4* __restrict__ acc, const float4* __restrict__ nxt, float scale) {
    size_t i = (size_t)blockIdx.x * blockDim.x + threadIdx.x;
    const size_t n4 = TOTAL / 4;
    if (i >= n4) return;
    float4 a = acc[i]; float4 b = nxt[i];
    a.x = (a.x + b.x) * scale; a.y = (a.y + b.y) * scale;
    a.z = (a.z + b.z) * scale; a.w = (a.w + b.w) * scale;
    acc[i] = a;
}

extern "C" void kernel_launch(void* const* d_in, const int* in_sizes, int n_in,
                              void* d_out, int out_size, void* d_ws, size_t ws_size,
                              hipStream_t stream) {
    const float* user_emb = (const float*)d_in[0];
    const float* item_emb = (const float*)d_in[1];
    const int*   rows     = (const int*)d_in[2];
    const int*   cols     = (const int*)d_in[3];
    const float* vals     = (const float*)d_in[4];
    float* out = (float*)d_out;

    const int BLK = 256;
    const size_t n4 = TOTAL / 4;
    dim3 g_init((n4 + BLK - 1) / BLK);

    // workspace layout — y1/y2 ALIAS padded ebuf1 (dead after row_sort)
    char* p = (char*)d_ws;
    unsigned int* epack = (unsigned int*)p;  p += (size_t)NNZ * sizeof(unsigned int);        // 19.2 MB
    __half* y1 = (__half*)p;                                                                  // aliases ebuf1
    int2*   ebuf1 = (int2*)p;                p += (size_t)NTILES * PAD * sizeof(int2);        // 48.0 MB
    __half* y2 = y1 + TOTAL;                                                                  // aliases ebuf1
    __half* cur16 = (__half*)p;              p += TOTAL * sizeof(__half);                     // 19.2 MB
    int*    tile_ptr = (int*)p;              p += (size_t)(NTILES + 1) * sizeof(int);
    int*    tile_cursor = (int*)p;           p += (size_t)NTILES * sizeof(int);
    int*    row_ptr = (int*)p;               p += (size_t)(N_NODES + 1) * sizeof(int);
    size_t needed = (size_t)(p - (char*)d_ws);

    if (ws_size < needed) {
        float* fcur = (float*)d_ws;
        float* fnxt = fcur + TOTAL;
        lgcn_init_f<<<g_init, BLK, 0, stream>>>((const float4*)user_emb, (const float4*)item_emb,
                                                (float4*)fcur, (float4*)out);
        const size_t st = (size_t)NNZ * EMB_DIM;
        dim3 g_scat((st + BLK - 1) / BLK);
        for (int l = 0; l < N_LAYERS; ++l) {
            hipMemsetAsync(fnxt, 0, TOTAL * sizeof(float), stream);
            lgcn_spmm_scatter<<<g_scat, BLK, 0, stream>>>(rows, cols, vals, fcur, fnxt);
            float scale = (l == N_LAYERS - 1) ? (1.0f / (N_LAYERS + 1)) : 1.0f;
            lgcn_accum<<<g_init, BLK, 0, stream>>>((float4*)out, (const float4*)fnxt, scale);
            float* t = fcur; fcur = fnxt; fnxt = t;
        }
        return;
    }

    // ---- padded bucketing + within-tile sort (no histogram pre-pass) ----
    hipMemsetAsync(tile_cursor, 0, (size_t)NTILES * sizeof(int), stream);
    int nBuckBlocks = (NNZ + EPB - 1) / EPB;   // 586
    edge_bucket<<<nBuckBlocks, BKT_BLK, 0, stream>>>(rows, cols, vals, tile_cursor, ebuf1);
    tile_scan<<<1, 1024, 0, stream>>>(tile_cursor, tile_ptr, row_ptr);
    row_sort<<<NTILES, RS_BLK, 0, stream>>>(ebuf1, tile_ptr, row_ptr, epack);

    // ---- init fp16 x0 (cur16 does NOT alias ebuf1; y1/y2 do, written after row_sort) ----
    lgcn_init_h<<<g_init, BLK, 0, stream>>>((const float4*)user_emb, (const float4*)item_emb,
                                            (uint2*)cur16);

    // ---- 3 layers; final layer fuses the combine ----
    const int WAVES_PER_BLK = BLK / 64;
    dim3 g_spmm((N_NODES + WAVES_PER_BLK - 1) / WAVES_PER_BLK);
    lgcn_spmm_h8<0><<<g_spmm, BLK, 0, stream>>>(row_ptr, epack,
        (const uint4*)cur16, (uint4*)y1, nullptr, nullptr, nullptr, nullptr);
    lgcn_spmm_h8<0><<<g_spmm, BLK, 0, stream>>>(row_ptr, epack,
        (const uint4*)y1, (uint4*)y2, nullptr, nullptr, nullptr, nullptr);
    lgcn_spmm_h8<1><<<g_spmm, BLK, 0, stream>>>(row_ptr, epack,
        (const uint4*)y2, nullptr,
        (const uint4*)cur16, (const uint4*)y1, (const uint4*)y2, (float4*)out);
}